// Round 9
// baseline (764.457 us; speedup 1.0000x reference)
//
#include <hip/hip_runtime.h>
#include <cstdint>
#include <cstddef>

#define NN   4096
#define LLC  50

// mega-kernel block partition (total 1152 <= 1280 = 5 blocks/CU guaranteed
// by __launch_bounds__(256,5) -> all blocks resident -> spin deps safe)
#define RNNB 256
#define SCB  320
#define G1B  320
#define G2B  256

__device__ __forceinline__ float bf2f(unsigned short u) {
    return __uint_as_float(((unsigned)u) << 16);
}
__device__ __forceinline__ unsigned short f2bf(float x) {
    unsigned b = __float_as_uint(x);
    return (unsigned short)((b + 0x7fffu + ((b >> 16) & 1u)) >> 16);
}

#if __has_builtin(__builtin_amdgcn_sdot4)
#define SDOT4(a, b, c) __builtin_amdgcn_sdot4((int)(a), (int)(b), (c), false)
#else
__device__ __forceinline__ int sdot4_sw(unsigned a, unsigned b, int c) {
    c += (int)(signed char)(a) * (int)(signed char)(b);
    c += (int)(signed char)(a >> 8) * (int)(signed char)(b >> 8);
    c += (int)(signed char)(a >> 16) * (int)(signed char)(b >> 16);
    c += (int)(signed char)(a >> 24) * (int)(signed char)(b >> 24);
    return c;
}
#define SDOT4(a, b, c) sdot4_sw((a), (b), (c))
#endif

#define DPPADD(v, ctrl, rmask) \
    ((v) + __builtin_amdgcn_update_dpp(0, (v), (ctrl), (rmask), 0xf, true))
__device__ __forceinline__ int wred64(int v) {
    v = DPPADD(v, 0x111, 0xf);
    v = DPPADD(v, 0x112, 0xf);
    v = DPPADD(v, 0x114, 0xf);
    v = DPPADD(v, 0x118, 0xf);
    v = DPPADD(v, 0x142, 0xa);
    v = DPPADD(v, 0x143, 0xc);   // lane63 = total
    return v;
}

__device__ __forceinline__ unsigned aload(const unsigned* p) {
    return __hip_atomic_load(p, __ATOMIC_RELAXED, __HIP_MEMORY_SCOPE_AGENT);
}
__device__ __forceinline__ void astore(unsigned* p, unsigned v) {
    __hip_atomic_store(p, v, __ATOMIC_RELAXED, __HIP_MEMORY_SCOPE_AGENT);
}

// ---- PREP: w8-repack + filt + xproj + hist fused (all independent) ----------
// blocks [0,4096): W_hh->int8 repack; [4096,4608): filt (32 rows/blk);
// [4608,5008): xproj; [5008,5264): hist.
__global__ __launch_bounds__(256) void k_prep(
        const float* __restrict__ W_hh, uint4* __restrict__ w8p,
        const float* __restrict__ fea, const float* __restrict__ W1,
        const float* __restrict__ W2, unsigned short* __restrict__ f1,
        unsigned short* __restrict__ f2,
        const float* __restrict__ item_emb, const int* __restrict__ joblst,
        const float* __restrict__ W_ih, const float* __restrict__ b_ih,
        const float* __restrict__ b_hh, float* __restrict__ xp,
        const int* __restrict__ i0, const int* __restrict__ i1,
        const int* __restrict__ i2, const int* __restrict__ i3,
        int* __restrict__ counts) {
    __shared__ float smem[4096];               // 16KB union
    unsigned blk = blockIdx.x;
    int t = threadIdx.x;
    if (blk < 4096) {
        // ---- W repack: Wp[row*256 + k4*64 + lane] = k-dwords lane*16+k4*4..+3
        unsigned T = blk * 256 + t;
        unsigned row = T >> 8, rem = T & 255;
        unsigned k4 = rem >> 6, lane = rem & 63;
        unsigned k0 = lane * 16 + k4 * 4;
        const float* src = W_hh + ((size_t)row * 1024 + k0) * 4;
        unsigned q[4];
#pragma unroll
        for (int i = 0; i < 4; ++i) {
            float4 w = *(const float4*)(src + i * 4);
            int q0 = (int)rintf(fminf(fmaxf(w.x * 8192.f, -127.f), 127.f));
            int q1 = (int)rintf(fminf(fmaxf(w.y * 8192.f, -127.f), 127.f));
            int q2 = (int)rintf(fminf(fmaxf(w.z * 8192.f, -127.f), 127.f));
            int q3 = (int)rintf(fminf(fmaxf(w.w * 8192.f, -127.f), 127.f));
            q[i] = (q0 & 0xff) | ((q1 & 0xff) << 8) | ((q2 & 0xff) << 16) | ((q3 & 0xff) << 24);
        }
        w8p[(size_t)row * 256 + k4 * 64 + lane] = make_uint4(q[0], q[1], q[2], q[3]);
    } else if (blk < 4608) {
        // ---- filt: 512 blocks, 2 half-blocks of 16 rows each
        int sub = t >> 7, tt = t & 127;
        int rb = (int)(blk - 4096) * 32 + sub * 16;
        float* sfea = smem + sub * 2048;
        for (int r = 0; r < 16; ++r) sfea[r * 128 + tt] = fea[(size_t)(rb + r) * 128 + tt];
        __syncthreads();
        float a1[16], a2[16];
#pragma unroll
        for (int r = 0; r < 16; ++r) { a1[r] = 0.f; a2[r] = 0.f; }
        for (int c = 0; c < 128; c += 4) {
            float w10 = W1[(c + 0) * 128 + tt], w11 = W1[(c + 1) * 128 + tt];
            float w12 = W1[(c + 2) * 128 + tt], w13 = W1[(c + 3) * 128 + tt];
            float w20 = W2[(c + 0) * 128 + tt], w21 = W2[(c + 1) * 128 + tt];
            float w22 = W2[(c + 2) * 128 + tt], w23 = W2[(c + 3) * 128 + tt];
#pragma unroll
            for (int r = 0; r < 16; ++r) {
                float4 f = *(const float4*)&sfea[r * 128 + c];
                a1[r] += f.x * w10 + f.y * w11 + f.z * w12 + f.w * w13;
                a2[r] += f.x * w20 + f.y * w21 + f.z * w22 + f.w * w23;
            }
        }
#pragma unroll
        for (int r = 0; r < 16; ++r) {
            f1[(size_t)(rb + r) * 128 + tt] = f2bf(a1[r]);
            f2[(size_t)(rb + r) * 128 + tt] = f2bf(a2[r]);
        }
    } else if (blk < 5008) {
        // ---- xproj: u = [0,400): nx = u&15, py = u>>4
        unsigned u = blk - 4608;
        int n = (int)(u & 15) * 256 + t;
        int p0 = (int)(u >> 4) * 8;
        float* sx = smem;                      // [8][128]
#pragma unroll
        for (int i = 0; i < 4; ++i) {
            int e2 = t + i * 256;
            int rr = e2 >> 7, c = e2 & 127;
            int p = p0 + rr;
            int b = p & 3, l = p >> 2;
            int j = joblst[b * LLC + l];
            sx[rr * 128 + c] = item_emb[(size_t)j * 128 + c];
        }
        __syncthreads();
        float acc[8];
#pragma unroll
        for (int r = 0; r < 8; ++r) acc[r] = 0.f;
        const float* wn = W_ih + (size_t)n * 128;
        for (int c = 0; c < 128; c += 4) {
            float4 w = *(const float4*)(wn + c);
#pragma unroll
            for (int r = 0; r < 8; ++r) {
                float4 xr = *(const float4*)&sx[r * 128 + c];
                acc[r] += xr.x * w.x + xr.y * w.y + xr.z * w.z + xr.w * w.w;
            }
        }
        float bias = b_ih[n] + b_hh[n];
#pragma unroll
        for (int r = 0; r < 8; ++r) xp[(size_t)(p0 + r) * NN + n] = acc[r] + bias;
    } else {
        // ---- hist: 256 blocks: s = v>>4, chunk = v&15
        int* lc = (int*)smem;
#pragma unroll
        for (int i = 0; i < 16; ++i) lc[t + i * 256] = 0;
        __syncthreads();
        unsigned v = blk - 5008;
        unsigned s = v >> 4, ch = v & 15;
        unsigned m = s >> 2, b = s & 3;
        const int* ip = (m == 0) ? i0 : (m == 1) ? i1 : (m == 2) ? i2 : i3;
        unsigned base = b * 131072u + ch * 4096u;
#pragma unroll
        for (int i = 0; i < 16; ++i) {
            int r = ip[base + t + i * 256];
            atomicAdd(&lc[r], 1);
        }
        __syncthreads();
        int* cs = counts + s * 4096;
#pragma unroll
        for (int i = 0; i < 16; ++i) {
            int vv = lc[t + i * 256];
            if (vv) atomicAdd(cs + t + i * 256, vv);
        }
    }
}

// ---- scan: counts -> rowptr + cursor ---------------------------------------
__global__ __launch_bounds__(256) void k_scan(const int* __restrict__ counts,
                                              int* __restrict__ rowptr,
                                              int* __restrict__ cursor) {
    int s = blockIdx.x, t = threadIdx.x;
    int loc[16];
    int base = t * 16;
    const int* cs = counts + s * 4096;
    int run = 0;
#pragma unroll
    for (int i = 0; i < 16; ++i) { loc[i] = run; run += cs[base + i]; }
    int total = run;
    int lane = t & 63, wv = t >> 6;
    int v = total;
#pragma unroll
    for (int d = 1; d < 64; d <<= 1) { int u = __shfl_up(v, d, 64); if (lane >= d) v += u; }
    __shared__ int wt[4];
    if (lane == 63) wt[wv] = v;
    __syncthreads();
    int pre = v - total;
    for (int i = 0; i < wv; ++i) pre += wt[i];
    int* rp = rowptr + s * 4097;
    int* cu = cursor + s * 4096;
#pragma unroll
    for (int i = 0; i < 16; ++i) { rp[base + i] = pre + loc[i]; cu[base + i] = pre + loc[i]; }
    if (t == 255) rp[4096] = pre + total;
}

// ---- MEGA: rnn (persistent) + scatter + gather1 + gather2 overlapped --------
// blocks [0,256): rnn (round-8 body, all-relaxed barrier, W in VGPRs).
// [256,576): scatter -> ep (sc1 stores, write-through: no L2 write amp).
// [576,896): gather1 (spins on scatter-done), y via sc1.
// [896,1152): gather2 (spins on gather1-done), res normal stores.
// Cross-XCD visibility: the round-7/8-proven protocol (sc1 store ->
// __syncthreads vmcnt drain -> relaxed-agent counter -> spin -> sc1 load).
// bar[]: [0..255] rnn groups, [256] rnn root, [272] scatter-done, [288] g1-done.
__global__ __launch_bounds__(256, 5) void k_mega(
        const uint4* __restrict__ Wp, const float* __restrict__ xp,
        unsigned* __restrict__ hq, float* __restrict__ hfin,
        int* __restrict__ bar,
        const int* __restrict__ i0, const int* __restrict__ i1,
        const int* __restrict__ i2, const int* __restrict__ i3,
        const float* __restrict__ v0, const float* __restrict__ v1,
        const float* __restrict__ v2, const float* __restrict__ v3,
        const float* __restrict__ d1, const float* __restrict__ d2,
        int* __restrict__ cursor, const int* __restrict__ rowptr,
        unsigned* __restrict__ ep,
        const unsigned* __restrict__ filt1, const unsigned* __restrict__ filt2,
        unsigned* __restrict__ y1, unsigned* __restrict__ y2,
        float* __restrict__ res) {
    __shared__ unsigned hs[4096];              // rnn h stage (16KB)
    __shared__ int red[4][16];
    __shared__ unsigned char hpk[4][4][4];
    int blk = blockIdx.x;
    int t = threadIdx.x;

    if (blk < RNNB) {
        // ================= RNN (unchanged round-8 body) =================
        int lane = t & 63, wv = t >> 6;
        int row_base = ((blk & 7) * 32 + (blk >> 3)) * 16;
        int wrow = row_base + wv * 4;
        uint4 W[4][4];
#pragma unroll
        for (int r = 0; r < 4; ++r)
#pragma unroll
            for (int k4 = 0; k4 < 4; ++k4)
                W[r][k4] = Wp[(size_t)(wrow + r) * 256 + k4 * 64 + lane];
        const float SC = 1.f / (8192.f * 127.f);
        for (int l = 0; l < LLC; ++l) {
            if (l > 0) {
                const unsigned* src = hq + (size_t)((l - 1) & 1) * 4096;
                unsigned sval[16];
#pragma unroll
                for (int k = 0; k < 16; ++k) sval[k] = aload(src + t + k * 256);
#pragma unroll
                for (int k = 0; k < 16; ++k) hs[t + k * 256] = sval[k];
                __syncthreads();
                uint4 H[4][4];
#pragma unroll
                for (int b = 0; b < 4; ++b)
#pragma unroll
                    for (int k4 = 0; k4 < 4; ++k4)
                        H[b][k4] = ((const uint4*)hs)[k4 * 256 + b * 64 + lane];
                int acc[4][4];
#pragma unroll
                for (int r = 0; r < 4; ++r)
#pragma unroll
                    for (int b = 0; b < 4; ++b) acc[r][b] = 0;
#pragma unroll
                for (int k4 = 0; k4 < 4; ++k4)
#pragma unroll
                    for (int r = 0; r < 4; ++r)
#pragma unroll
                        for (int b = 0; b < 4; ++b) {
                            acc[r][b] = SDOT4(W[r][k4].x, H[b][k4].x, acc[r][b]);
                            acc[r][b] = SDOT4(W[r][k4].y, H[b][k4].y, acc[r][b]);
                            acc[r][b] = SDOT4(W[r][k4].z, H[b][k4].z, acc[r][b]);
                            acc[r][b] = SDOT4(W[r][k4].w, H[b][k4].w, acc[r][b]);
                        }
#pragma unroll
                for (int r = 0; r < 4; ++r)
#pragma unroll
                    for (int b = 0; b < 4; ++b) acc[r][b] = wred64(acc[r][b]);
                if (lane == 63) {
#pragma unroll
                    for (int b = 0; b < 4; ++b) {
                        int4 q = { acc[0][b], acc[1][b], acc[2][b], acc[3][b] };
                        *(int4*)&red[wv][b * 4] = q;
                    }
                }
            }
            if (lane < 16) {
                int b = lane >> 2, rr = lane & 3;
                int row = wrow + rr;
                float a = (l > 0) ? (float)red[wv][lane] * SC : 0.f;
                float pre = a + xp[(size_t)(l * 4 + b) * NN + row];
                float hnew = tanhf(pre);
                if (l == LLC - 1) hfin[(size_t)b * NN + row] = hnew;
                int q = (int)rintf(hnew * 127.f);
                hpk[wv][b][rr] = (unsigned char)(q & 0xff);
            }
            if (l < LLC - 1) {
                if (lane < 4) {
                    int b = lane;
                    unsigned d = *(const unsigned*)&hpk[wv][b][0];
                    int hk = (row_base >> 2) + wv;
                    int phys = ((hk >> 2) & 3) * 1024 + b * 256 + (hk >> 4) * 4 + (hk & 3);
                    astore(hq + (size_t)(l & 1) * 4096 + phys, d);
                }
                __syncthreads();
                if (t == 0) {
                    int g = blk & 7;
                    int old = __hip_atomic_fetch_add(&bar[g * 32], 1, __ATOMIC_RELAXED,
                                                     __HIP_MEMORY_SCOPE_AGENT);
                    if ((old & 31) == 31)
                        __hip_atomic_fetch_add(&bar[256], 1, __ATOMIC_RELAXED,
                                               __HIP_MEMORY_SCOPE_AGENT);
                    int target = 8 * (l + 1);
                    while (__hip_atomic_load(&bar[256], __ATOMIC_RELAXED,
                                             __HIP_MEMORY_SCOPE_AGENT) < target)
                        __builtin_amdgcn_s_sleep(2);
                }
                __syncthreads();
            }
        }
    } else if (blk < RNNB + SCB) {
        // ================= scatter: COO -> CSR-packed ep (sc1) ==========
        for (unsigned gid = (unsigned)(blk - RNNB) * 256 + t; gid < 16u * 65536u;
             gid += SCB * 256) {
            unsigned s = gid >> 16, e = gid & 65535;
            unsigned m = s >> 2, b = s & 3;
            const int* ip = (m == 0) ? i0 : (m == 1) ? i1 : (m == 2) ? i2 : i3;
            const float* vp = (m == 0) ? v0 : (m == 1) ? v1 : (m == 2) ? v2 : v3;
            int r = ip[(size_t)b * 131072 + e];
            int c = ip[(size_t)b * 131072 + 65536 + e];
            float v = vp[(size_t)b * 65536 + e];
            if (m == 1) v *= d1[c];
            if (m == 3) v *= d2[c];
            int pos = atomicAdd(cursor + s * 4096 + r, 1);
            astore(ep + (size_t)s * 65536 + pos, ((unsigned)c << 16) | (unsigned)f2bf(v));
        }
        __syncthreads();                       // vmcnt drain: ep at coherence pt
        if (t == 0)
            __hip_atomic_fetch_add(&bar[272], 1, __ATOMIC_RELAXED,
                                   __HIP_MEMORY_SCOPE_AGENT);
    } else if (blk < RNNB + SCB + G1B) {
        // ================= gather1: y = inv @ filt (64-thr tasks) =======
        if (t == 0)
            while (__hip_atomic_load(&bar[272], __ATOMIC_RELAXED,
                                     __HIP_MEMORY_SCOPE_AGENT) < SCB)
                __builtin_amdgcn_s_sleep(2);
        __syncthreads();
        int sub = t >> 6, fp = t & 63;
        for (unsigned tau = (unsigned)(blk - RNNB - SCB) * 4 + sub; tau < 32768;
             tau += G1B * 4) {
            unsigned q = tau >> 12, row = tau & 4095;
            int s = (q < 4) ? (int)q : (int)q + 4;         // inv1: 0..3, inv2: 8..11
            unsigned b = q & 3;
            const unsigned* X = (q < 4) ? filt1 : filt2;   // bf16-pair dwords
            unsigned* Y = (q < 4) ? y1 : y2;
            const int* rp = rowptr + s * 4097;
            int e0 = rp[row], e1 = rp[row + 1];
            float a0 = 0.f, a1 = 0.f;
            for (int e = e0; e < e1; ++e) {
                unsigned pp = aload(ep + (size_t)s * 65536 + e);
                float v = bf2f((unsigned short)(pp & 0xffffu));
                unsigned c = pp >> 16;
                unsigned u = X[((size_t)(b << 12) + c) * 64 + fp];
                a0 += v * bf2f((unsigned short)(u & 0xffffu));
                a1 += v * bf2f((unsigned short)(u >> 16));
            }
            unsigned out = (unsigned)f2bf(a0) | ((unsigned)f2bf(a1) << 16);
            astore(Y + ((size_t)(b << 12) + row) * 64 + fp, out);
        }
        __syncthreads();                       // vmcnt drain: y at coherence pt
        if (t == 0)
            __hip_atomic_fetch_add(&bar[288], 1, __ATOMIC_RELAXED,
                                   __HIP_MEMORY_SCOPE_AGENT);
    } else {
        // ================= gather2: res = phi1@y1 + phi2@y2 =============
        if (t == 0)
            while (__hip_atomic_load(&bar[288], __ATOMIC_RELAXED,
                                     __HIP_MEMORY_SCOPE_AGENT) < G1B)
                __builtin_amdgcn_s_sleep(2);
        __syncthreads();
        int sub = t >> 6, fp = t & 63;
        for (unsigned tau = (unsigned)(blk - RNNB - SCB - G1B) * 4 + sub; tau < 16384;
             tau += G2B * 4) {
            unsigned b = tau >> 12, row = tau & 4095;
            float a0 = 0.f, a1 = 0.f;
#pragma unroll
            for (int half = 0; half < 2; ++half) {
                int s = (half ? 12 : 4) + (int)b;
                const unsigned* Y = half ? y2 : y1;
                const int* rp = rowptr + s * 4097;
                int e0 = rp[row], e1 = rp[row + 1];
                for (int e = e0; e < e1; ++e) {
                    unsigned pp = aload(ep + (size_t)s * 65536 + e);
                    float v = bf2f((unsigned short)(pp & 0xffffu));
                    unsigned c = pp >> 16;
                    unsigned u = aload(Y + ((size_t)(b << 12) + c) * 64 + fp);
                    a0 += v * bf2f((unsigned short)(u & 0xffffu));
                    a1 += v * bf2f((unsigned short)(u >> 16));
                }
            }
            float2 o = { a0, a1 };
            ((float2*)res)[((size_t)(b << 12) + row) * 64 + fp] = o;
        }
    }
}

// ---- out[b,n,k] = sigmoid( gelu(res.dW[k]+db) * gelu(Emb) ), LDS-staged ----
__global__ __launch_bounds__(256) void k_final(const float* __restrict__ res,
                                               const float* __restrict__ dW,
                                               const float* __restrict__ db,
                                               const float* __restrict__ hfin,
                                               float* __restrict__ out) {
    __shared__ float4 sres4[512];
    __shared__ float sdw[10 * 132];
    int t = threadIdx.x;
    int row0 = blockIdx.x * 16;
    {
        const float4* src = (const float4*)(res + (size_t)row0 * 128);
        sres4[t] = src[t];
        sres4[t + 256] = src[t + 256];
    }
    for (int i = t; i < 1280; i += 256) { int k = i >> 7, c = i & 127; sdw[k * 132 + c] = dW[i]; }
    __syncthreads();
    int r = t >> 4, k = t & 15;
    if (k < 10) {
        const float* rr = (const float*)sres4 + r * 128;
        const float* wk = sdw + k * 132;
        float acc = 0.f;
#pragma unroll
        for (int c = 0; c < 128; c += 4) {
            float4 a = *(const float4*)(rr + c);
            float4 w = *(const float4*)(wk + c);
            acc += a.x * w.x + a.y * w.y + a.z * w.z + a.w * w.w;
        }
        float pre = acc + db[k];
        int grow = row0 + r;
        int b = grow >> 12, n = grow & 4095;
        float e = hfin[(size_t)b * NN + n];
        float g1 = 0.5f * pre * (1.f + erff(pre * 0.70710678118f));
        float ge = 0.5f * e * (1.f + erff(e * 0.70710678118f));
        out[(size_t)grow * 10 + k] = 1.f / (1.f + __expf(-g1 * ge));
    }
}

extern "C" void kernel_launch(void* const* d_in, const int* in_sizes, int n_in,
                              void* d_out, int out_size, void* d_ws, size_t ws_size,
                              hipStream_t stream) {
    const int*   phi1_idx = (const int*)d_in[0];
    const float* phi1_val = (const float*)d_in[1];
    const int*   inv1_idx = (const int*)d_in[2];
    const float* inv1_val = (const float*)d_in[3];
    const int*   phi2_idx = (const int*)d_in[4];
    const float* phi2_val = (const float*)d_in[5];
    const int*   inv2_idx = (const int*)d_in[6];
    const float* inv2_val = (const float*)d_in[7];
    const float* fea      = (const float*)d_in[8];
    const int*   joblst   = (const int*)d_in[9];
    const float* W1       = (const float*)d_in[10];
    const float* d1       = (const float*)d_in[11];
    const float* W2       = (const float*)d_in[12];
    const float* d2       = (const float*)d_in[13];
    const float* W_ih     = (const float*)d_in[14];
    const float* W_hh     = (const float*)d_in[15];
    const float* b_ih     = (const float*)d_in[16];
    const float* b_hh     = (const float*)d_in[17];
    const float* dense_W  = (const float*)d_in[18];
    const float* dense_b  = (const float*)d_in[19];
    const float* item_emb = (const float*)d_in[20];

    float* ws = (float*)d_ws;                       // slot = 4B
    unsigned short* filt1 = (unsigned short*)ws;            // 1,048,576 slots
    unsigned short* filt2 = (unsigned short*)(ws + 1048576);
    unsigned short* y1    = (unsigned short*)(ws + 2097152);
    unsigned short* y2    = (unsigned short*)(ws + 3145728);
    float* res  = ws + 4194304;                     // 2,097,152 slots
    float* xp   = ws + 6291456;                     // 819,200
    float* hfin = ws + 7110656;                     // 16,384
    unsigned* hq  = (unsigned*)(ws + 7127040);      // 8,192
    uint4* w8p = (uint4*)(ws + 7135232);            // 16MB repacked int8 W
    int*   counts = (int*)(ws + 11329536);          // 65,536
    int*   rowptr = (int*)(ws + 11395072);          // 65,552
    int*   cursor = (int*)(ws + 11460624);          // 65,536
    unsigned* ep  = (unsigned*)(ws + 11526160);     // 1,048,576
    int*   bar    = (int*)(ws + 12574736);          // 512 ints

    hipMemsetAsync(counts, 0, 16 * 4096 * sizeof(int), stream);
    hipMemsetAsync(bar, 0, 2048, stream);

    // prep: W repack + filt + xproj + hist, one launch
    k_prep<<<5264, 256, 0, stream>>>(W_hh, w8p, fea, W1, W2, filt1, filt2,
                                     item_emb, joblst, W_ih, b_ih, b_hh, xp,
                                     inv1_idx, phi1_idx, inv2_idx, phi2_idx, counts);
    k_scan<<<16, 256, 0, stream>>>(counts, rowptr, cursor);

    // mega: rnn + scatter + gather1 + gather2, overlapped in one launch
    k_mega<<<RNNB + SCB + G1B + G2B, 256, 0, stream>>>(
        w8p, xp, hq, hfin, bar,
        inv1_idx, phi1_idx, inv2_idx, phi2_idx,
        inv1_val, phi1_val, inv2_val, phi2_val,
        d1, d2, cursor, rowptr, ep,
        (const unsigned*)filt1, (const unsigned*)filt2,
        (unsigned*)y1, (unsigned*)y2, res);

    k_final<<<1024, 256, 0, stream>>>(res, dense_W, dense_b, hfin, (float*)d_out);
}